// Round 11
// baseline (993.636 us; speedup 1.0000x reference)
//
#include <hip/hip_runtime.h>
#include <math.h>

// MS-SSIM loss, 5 levels, 11x11 separable Gaussian, zero padding.
// R11 = R5 (the only verified scratch-free structure: named-scalar ring,
// ephemeral scalar tap loads in base-ptr+immediate form, MASKED/interior
// split) + ONE change: the v-conv is phase-shifted one row. Body j issues
// row (y0+5+j)'s 22 tap loads, then runs the v-conv + stats for OUTPUT row
// j-1 using only the ring (independent of the in-flight loads -> ~55 VALU
// of latency cover), then h-convolves the taps into the slot holding the
// dead oldest row. No arrays, no vector types, no value other than the ring
// lives across a row boundary (scratch rules from R2/R4/R8/R9/R10).

#define NIMG 48            // 16 * 3
#define TWO_C1 2.0e-4f     // 2 * (0.01*1.0)^2
#define TWO_C2 1.8e-3f     // 2 * (0.03*1.0)^2

struct CInfo { int base[5]; int cnt[5]; };

#define FOR11(X) X(0) X(1) X(2) X(3) X(4) X(5) X(6) X(7) X(8) X(9) X(10)

#define DECLR(K) float rA##K = 0.f, rB##K = 0.f, rP##K = 0.f, rQ##K = 0.f;

// Ephemeral per-row taps (assignment form; declared inside each body).
#define TDECL(K) float p##K, t##K;
#define LD_I(K) p##K = rpl_[K]; t##K = rtl_[K];
#define LD_M(K) { const int x_ = gx + (K) - 5; \
    const int xc_ = min(max(x_, 0), W - 1); \
    const float pv_ = rp_[xc_], tv_ = rt_[xc_]; \
    const bool ok_ = ((unsigned)x_ < (unsigned)W); \
    p##K = ok_ ? pv_ : 0.f; t##K = ok_ ? tv_ : 0.f; }
#define LD_Z(K) p##K = 0.f; t##K = 0.f;

// Load taps of row RR (R5's exact addressing: one per-lane base + imm offs).
#define LOADTAPS(RR) \
    const int r_ = (RR); \
    FOR11(TDECL) \
    if ((unsigned)r_ < (unsigned)H) { \
      const float* rp_ = Pi + (size_t)r_ * W; \
      const float* rt_ = Ti + (size_t)r_ * W; \
      if (MASKED) { FOR11(LD_M) } \
      else { const float* rpl_ = rp_ + gx - 5; \
             const float* rtl_ = rt_ + gx - 5; \
             FOR11(LD_I) } \
    } else { FOR11(LD_Z) }

#define HACC(K) { \
    const float a_ = p##K + t##K; \
    const float b_ = p##K - t##K; \
    hA_ = __builtin_fmaf(G##K, a_, hA_); \
    hB_ = __builtin_fmaf(G##K, b_, hB_); \
    hP_ = __builtin_fmaf(G##K * a_, a_, hP_); \
    hQ_ = __builtin_fmaf(G##K * b_, b_, hQ_); }

// H-conv current taps -> ring slot SW; fused 2x2 avg-pool (uses p5/t5, r_).
#define HCONVW(SW) { \
    float hA_ = 0.f, hB_ = 0.f, hP_ = 0.f, hQ_ = 0.f; \
    FOR11(HACC) \
    rA##SW = hA_; rB##SW = hB_; rP##SW = hP_; rQ##SW = hQ_; \
    if (DS) { \
      if (r_ >= y0 && r_ < y0 + nout) { \
        if ((r_ & 1) == 0) { pr = p5; tr = t5; } \
        else { \
          float sp_ = pr + p5, st_ = tr + t5; \
          sp_ += __shfl_xor(sp_, 1, 64); \
          st_ += __shfl_xor(st_, 1, 64); \
          if (((lane & 1) == 0) && (gx < W)) { \
            const size_t o_ = obase + (size_t)(r_ >> 1) * (size_t)(W >> 1) + \
                              (size_t)(gx >> 1); \
            dsP[o_] = sp_ * 0.25f; \
            dsT[o_] = st_ * 0.25f; \
          } } } } }

#define VSTEP(GK, S) \
    vA_ = __builtin_fmaf(GK, rA##S, vA_); vB_ = __builtin_fmaf(GK, rB##S, vB_); \
    vP_ = __builtin_fmaf(GK, rP##S, vP_); vQ_ = __builtin_fmaf(GK, rQ##S, vQ_);

// Prologue row: load + h-conv into slot SW (no v-conv).
#define PSTEP(RR, SW) do { LOADTAPS(RR) HCONVW(SW) } while (0)

// Body j = base+JJ: issue row (y0+5+j) loads; v-conv + stats for OUTPUT row
// j-1 over ring slots S0..S10 (rows j-6..j+4, independent of the loads);
// h-conv the taps into S0 (slot of dead row j-6).
#define ROWD(JJ, S0,S1,S2,S3,S4,S5,S6,S7,S8,S9,S10) do { \
    const int i_ = base + (JJ); \
    LOADTAPS(y0 + 5 + i_) \
    float vA_ = G0 * rA##S0, vB_ = G0 * rB##S0; \
    float vP_ = G0 * rP##S0, vQ_ = G0 * rQ##S0; \
    VSTEP(G1, S1) VSTEP(G2, S2) VSTEP(G3, S3) VSTEP(G4, S4) VSTEP(G5, S5) \
    VSTEP(G6, S6) VSTEP(G7, S7) VSTEP(G8, S8) VSTEP(G9, S9) VSTEP(G10, S10) \
    const float A2_ = vA_ * vA_, B2_ = vB_ * vB_; \
    const float dAB_ = A2_ - B2_, sAB_ = A2_ + B2_; \
    const float cn_ = (vP_ - vQ_) - dAB_ + TWO_C2; \
    const float cd_ = (vP_ + vQ_) - sAB_ + TWO_C2; \
    float val_; \
    if (LAST) val_ = ((dAB_ + TWO_C1) * cn_) / ((sAB_ + TWO_C1) * cd_); \
    else      val_ = cn_ / cd_; \
    if ((i_ >= 1) && (i_ - 1 < nout) && (!MASKED || gx < W)) sum += val_; \
    HCONVW(S0) \
  } while (0)

template <int MASKED, int DS, int LAST>
__device__ __forceinline__ float strip_run(
    const float* __restrict__ Pi, const float* __restrict__ Ti,
    const int H, const int W, const int y0, const int nout, const int c0,
    float* __restrict__ dsP, float* __restrict__ dsT, const size_t obase,
    const float G0, const float G1, const float G2, const float G3,
    const float G4, const float G5, const float G6, const float G7,
    const float G8, const float G9, const float G10) {
  const int lane = threadIdx.x & 63;
  const int gx = c0 + lane;
  FOR11(DECLR)                       // ring rA0..rQ10, named scalars
  float pr = 0.f, tr = 0.f, sum = 0.f;

  // Slot 0 (row y0-6) feeds only the discarded output -1: seed zeros.
  // Prologue: slots 1..10 <- rows y0-5 .. y0+4.
  PSTEP(y0 - 5, 1); PSTEP(y0 - 4, 2); PSTEP(y0 - 3, 3); PSTEP(y0 - 2, 4);
  PSTEP(y0 - 1, 5); PSTEP(y0 + 0, 6); PSTEP(y0 + 1, 7); PSTEP(y0 + 2, 8);
  PSTEP(y0 + 3, 9); PSTEP(y0 + 4, 10);

  // Main: bodies j=0..nout (output rows -1..nout-1, first discarded).
  for (int base = 0; base < nout + 1; base += 11) {
    ROWD(0,  0,1,2,3,4,5,6,7,8,9,10);
    ROWD(1,  1,2,3,4,5,6,7,8,9,10,0);
    ROWD(2,  2,3,4,5,6,7,8,9,10,0,1);
    ROWD(3,  3,4,5,6,7,8,9,10,0,1,2);
    ROWD(4,  4,5,6,7,8,9,10,0,1,2,3);
    ROWD(5,  5,6,7,8,9,10,0,1,2,3,4);
    ROWD(6,  6,7,8,9,10,0,1,2,3,4,5);
    ROWD(7,  7,8,9,10,0,1,2,3,4,5,6);
    ROWD(8,  8,9,10,0,1,2,3,4,5,6,7);
    ROWD(9,  9,10,0,1,2,3,4,5,6,7,8);
    ROWD(10, 10,0,1,2,3,4,5,6,7,8,9);
  }
  return sum;
}

template <int DS, int LAST>
__global__ __launch_bounds__(256, 3)
void msssim_level_k(const float* __restrict__ P, const float* __restrict__ T,
                    const int H, const int W, const int strips,
                    const int chunks, const int chunkH, const int tasks,
                    float* __restrict__ dsP, float* __restrict__ dsT,
                    double* __restrict__ partial,
                    const float G0, const float G1, const float G2,
                    const float G3, const float G4, const float G5,
                    const float G6, const float G7, const float G8,
                    const float G9, const float G10) {
  __shared__ float sRed[4];
  const int tid = threadIdx.x;
  const int lane = tid & 63;
  const int wid = tid >> 6;
  float sum = 0.f;
  const int task = blockIdx.x * 4 + wid;
  if (task < tasks) {
    const int strip = task % strips;
    const int rem = task / strips;
    const int chunk = rem % chunks;
    const int img = rem / chunks;
    const int y0 = chunk * chunkH;
    const int nout = min(chunkH, H - y0);
    const size_t ibase = (size_t)img * H * W;
    const size_t obase = DS ? (size_t)img * (size_t)(H >> 1) * (W >> 1) : 0;
    const bool edge = (strip == 0) || (strip * 64 + 69 > W);  // wave-uniform
    if (edge)
      sum = strip_run<1, DS, LAST>(P + ibase, T + ibase, H, W, y0, nout,
                                   strip * 64, dsP, dsT, obase,
                                   G0, G1, G2, G3, G4, G5, G6, G7, G8, G9, G10);
    else
      sum = strip_run<0, DS, LAST>(P + ibase, T + ibase, H, W, y0, nout,
                                   strip * 64, dsP, dsT, obase,
                                   G0, G1, G2, G3, G4, G5, G6, G7, G8, G9, G10);
  }
#pragma unroll
  for (int off = 32; off; off >>= 1) sum += __shfl_down(sum, off, 64);
  if (lane == 0) sRed[wid] = sum;
  __syncthreads();
  if (tid == 0)
    partial[blockIdx.x] = (double)(sRed[0] + sRed[1] + sRed[2] + sRed[3]);
}

__global__ void msssim_combine_k(const double* __restrict__ partial,
                                 float* __restrict__ out, const CInfo ci) {
  const int lane = threadIdx.x & 63;
  double lv[5];
#pragma unroll
  for (int L = 0; L < 5; ++L) {
    double s = 0.0;
    for (int i = lane; i < ci.cnt[L]; i += 64) s += partial[ci.base[L] + i];
#pragma unroll
    for (int off = 32; off; off >>= 1) s += __shfl_down(s, off, 64);
    lv[L] = s;
  }
  if (lane == 0) {
    double ms = lv[4] / (48.0 * 32.0 * 32.0);
    ms *= pow(lv[0] / (48.0 * 512.0 * 512.0), (double)0.0448f);
    ms *= pow(lv[1] / (48.0 * 256.0 * 256.0), (double)0.2856f);
    ms *= pow(lv[2] / (48.0 * 128.0 * 128.0), (double)0.3001f);
    ms *= pow(lv[3] / (48.0 * 64.0 * 64.0),  (double)0.2363f);
    out[0] = (float)(1.0 - ms);
  }
}

extern "C" void kernel_launch(void* const* d_in, const int* in_sizes, int n_in,
                              void* d_out, int out_size, void* d_ws, size_t ws_size,
                              hipStream_t stream) {
  const float* pred = (const float*)d_in[0];
  const float* targ = (const float*)d_in[1];
  float* out = (float*)d_out;

  char* ws = (char*)d_ws;
  double* partial = (double*)ws;  // per-block partial sums, 32KB region
  size_t off = 32768;
  auto alloc = [&](size_t elems) {
    float* p = (float*)(ws + off);
    off += elems * sizeof(float);
    return p;
  };
  float* L1p = alloc((size_t)NIMG * 256 * 256);
  float* L1t = alloc((size_t)NIMG * 256 * 256);
  float* L2p = alloc((size_t)NIMG * 128 * 128);
  float* L2t = alloc((size_t)NIMG * 128 * 128);
  float* L3p = alloc((size_t)NIMG * 64 * 64);
  float* L3t = alloc((size_t)NIMG * 64 * 64);
  float* L4p = alloc((size_t)NIMG * 32 * 32);
  float* L4t = alloc((size_t)NIMG * 32 * 32);

  float g[11];
  {
    double gd[11], s = 0.0;
    for (int k = 0; k < 11; ++k) {
      const double c = (double)(k - 5);
      gd[k] = exp(-(c * c) / 4.5);  // 2*sigma^2 = 4.5
      s += gd[k];
    }
    for (int k = 0; k < 11; ++k) g[k] = (float)(gd[k] / s);
  }

  CInfo ci;
  int slotOff = 0;

  auto launchLevel = [&](const float* P, const float* T, int H, int W,
                         int chunkH, float* dP, float* dT, int L, bool last) {
    const int strips = (W + 63) / 64;
    const int chunks = (H + chunkH - 1) / chunkH;
    const int tasks = strips * chunks * NIMG;
    const int blocks = (tasks + 3) / 4;
    ci.base[L] = slotOff;
    ci.cnt[L] = blocks;
    if (last) {
      msssim_level_k<0, 1><<<blocks, 256, 0, stream>>>(
          P, T, H, W, strips, chunks, chunkH, tasks, nullptr, nullptr,
          partial + slotOff, g[0], g[1], g[2], g[3], g[4], g[5], g[6], g[7],
          g[8], g[9], g[10]);
    } else {
      msssim_level_k<1, 0><<<blocks, 256, 0, stream>>>(
          P, T, H, W, strips, chunks, chunkH, tasks, dP, dT,
          partial + slotOff, g[0], g[1], g[2], g[3], g[4], g[5], g[6], g[7],
          g[8], g[9], g[10]);
    }
    slotOff += blocks;
  };

  launchLevel(pred, targ, 512, 512, 32, L1p, L1t, 0, false);
  launchLevel(L1p, L1t, 256, 256, 32, L2p, L2t, 1, false);
  launchLevel(L2p, L2t, 128, 128, 32, L3p, L3t, 2, false);
  launchLevel(L3p, L3t, 64, 64, 16, L4p, L4t, 3, false);
  launchLevel(L4p, L4t, 32, 32, 8, nullptr, nullptr, 4, true);

  msssim_combine_k<<<1, 64, 0, stream>>>(partial, out, ci);
}

// Round 12
// 564.016 us; speedup vs baseline: 1.7617x; 1.7617x over previous
//
#include <hip/hip_runtime.h>
#include <math.h>

// MS-SSIM loss, 5 levels, 11x11 separable Gaussian, zero padding.
// R12 = R5's guarded structure (verbatim — the only verified scratch-free
// form) for boundary tasks, plus a BRANCH-FREE "safe" body for tasks where
// no bounds check is needed (interior strip && all rows y0-5..y0+5+maxbody
// in-bounds; wave-uniform test). Scratch root-cause from R2..R11 diffs:
// tap values crossing a control-flow join (if/else zero-fill) become phis
// and get demoted to scratch; branch-local (R5) or branch-FREE (this safe
// path) tap lifetimes stay in registers. The safe body reorders: issue 22
// scalar loads -> 44 ring-only v-conv FMAs for output j-1 (latency cover,
// independent of the loads) -> h-conv into the dead ring slot.
// Also chunkH 32->64 (launcher-only): prologue overhead 10/33 -> 10/66.

#define NIMG 48            // 16 * 3
#define TWO_C1 2.0e-4f     // 2 * (0.01*1.0)^2
#define TWO_C2 1.8e-3f     // 2 * (0.03*1.0)^2

struct CInfo { int base[5]; int cnt[5]; };

#define FOR11(X) X(0) X(1) X(2) X(3) X(4) X(5) X(6) X(7) X(8) X(9) X(10)

#define DECLR(K) float rA##K = 0.f, rB##K = 0.f, rP##K = 0.f, rQ##K = 0.f;

#define HACC(K) { \
    const float a_ = p##K + t##K; \
    const float b_ = p##K - t##K; \
    hA_ = __builtin_fmaf(G##K, a_, hA_); \
    hB_ = __builtin_fmaf(G##K, b_, hB_); \
    hP_ = __builtin_fmaf(G##K * a_, a_, hP_); \
    hQ_ = __builtin_fmaf(G##K * b_, b_, hQ_); }

#define VSTEP(GK, S) \
    vA_ = __builtin_fmaf(GK, rA##S, vA_); vB_ = __builtin_fmaf(GK, rB##S, vB_); \
    vP_ = __builtin_fmaf(GK, rP##S, vP_); vQ_ = __builtin_fmaf(GK, rQ##S, vQ_);

#define SSIM_STATS \
    const float A2_ = vA_ * vA_, B2_ = vB_ * vB_; \
    const float dAB_ = A2_ - B2_, sAB_ = A2_ + B2_; \
    const float cn_ = (vP_ - vQ_) - dAB_ + TWO_C2; \
    const float cd_ = (vP_ + vQ_) - sAB_ + TWO_C2; \
    float val_; \
    if (LAST) val_ = ((dAB_ + TWO_C1) * cn_) / ((sAB_ + TWO_C1) * cd_); \
    else      val_ = cn_ / cd_;

// ---------------- guarded path (R5 verbatim) ----------------
#define TAPLOAD_I(K) \
  const float p##K = rpl_[K]; const float t##K = rtl_[K];
#define TAPLOAD_M(K) \
  float p##K, t##K; { \
    const int x_ = gx + (K) - 5; \
    const int xc_ = min(max(x_, 0), W - 1); \
    const float pv_ = rp_[xc_], tv_ = rt_[xc_]; \
    const bool ok_ = ((unsigned)x_ < (unsigned)W); \
    p##K = ok_ ? pv_ : 0.f; t##K = ok_ ? tv_ : 0.f; }

#define MS_STEP_N(R, SW) do { \
    const int r_ = (R); \
    float hA_ = 0.f, hB_ = 0.f, hP_ = 0.f, hQ_ = 0.f; \
    float pc_ = 0.f, tc_ = 0.f; \
    if ((unsigned)r_ < (unsigned)H) { \
      const float* rp_ = Pi + (size_t)r_ * W; \
      const float* rt_ = Ti + (size_t)r_ * W; \
      if (MASKED) { \
        FOR11(TAPLOAD_M) \
        FOR11(HACC) \
        pc_ = p5; tc_ = t5; \
      } else { \
        const float* rpl_ = rp_ + gx - 5; \
        const float* rtl_ = rt_ + gx - 5; \
        FOR11(TAPLOAD_I) \
        FOR11(HACC) \
        pc_ = p5; tc_ = t5; \
      } \
    } \
    rA##SW = hA_; rB##SW = hB_; rP##SW = hP_; rQ##SW = hQ_; \
    if (DS) { \
      if (r_ >= y0 && r_ < y0 + nout) { \
        if ((r_ & 1) == 0) { pr = pc_; tr = tc_; } \
        else { \
          float sp_ = pr + pc_, st_ = tr + tc_; \
          sp_ += __shfl_xor(sp_, 1, 64); \
          st_ += __shfl_xor(st_, 1, 64); \
          if (((lane & 1) == 0) && (gx < W)) { \
            const size_t o_ = obase + (size_t)(r_ >> 1) * (size_t)(W >> 1) + \
                              (size_t)(gx >> 1); \
            dsP[o_] = sp_ * 0.25f; \
            dsT[o_] = st_ * 0.25f; \
          } } } } \
  } while (0)

#define ROW_G(IROW, SW, S0,S1,S2,S3,S4,S5,S6,S7,S8,S9) do { \
    const int i_ = (IROW); \
    const bool live_ = (i_ < nout); \
    MS_STEP_N(y0 + 5 + i_, SW); \
    float vA_ = G0 * rA##S0, vB_ = G0 * rB##S0; \
    float vP_ = G0 * rP##S0, vQ_ = G0 * rQ##S0; \
    VSTEP(G1, S1) VSTEP(G2, S2) VSTEP(G3, S3) VSTEP(G4, S4) VSTEP(G5, S5) \
    VSTEP(G6, S6) VSTEP(G7, S7) VSTEP(G8, S8) VSTEP(G9, S9) VSTEP(G10, SW) \
    SSIM_STATS \
    if ((!MASKED || gx < W) && live_) sum += val_; \
  } while (0)

template <int MASKED, int DS, int LAST>
__device__ __forceinline__ float strip_guard(
    const float* __restrict__ Pi, const float* __restrict__ Ti,
    const int H, const int W, const int y0, const int nout, const int c0,
    float* __restrict__ dsP, float* __restrict__ dsT, const size_t obase,
    const float G0, const float G1, const float G2, const float G3,
    const float G4, const float G5, const float G6, const float G7,
    const float G8, const float G9, const float G10) {
  const int lane = threadIdx.x & 63;
  const int gx = c0 + lane;
  FOR11(DECLR)
  float pr = 0.f, tr = 0.f, sum = 0.f;

  MS_STEP_N(y0 - 5, 0); MS_STEP_N(y0 - 4, 1); MS_STEP_N(y0 - 3, 2);
  MS_STEP_N(y0 - 2, 3); MS_STEP_N(y0 - 1, 4); MS_STEP_N(y0 + 0, 5);
  MS_STEP_N(y0 + 1, 6); MS_STEP_N(y0 + 2, 7); MS_STEP_N(y0 + 3, 8);
  MS_STEP_N(y0 + 4, 9);

  for (int base = 0; base < nout; base += 11) {
    ROW_G(base + 0, 10, 0,1,2,3,4,5,6,7,8,9);
    ROW_G(base + 1, 0,  1,2,3,4,5,6,7,8,9,10);
    ROW_G(base + 2, 1,  2,3,4,5,6,7,8,9,10,0);
    ROW_G(base + 3, 2,  3,4,5,6,7,8,9,10,0,1);
    ROW_G(base + 4, 3,  4,5,6,7,8,9,10,0,1,2);
    ROW_G(base + 5, 4,  5,6,7,8,9,10,0,1,2,3);
    ROW_G(base + 6, 5,  6,7,8,9,10,0,1,2,3,4);
    ROW_G(base + 7, 6,  7,8,9,10,0,1,2,3,4,5);
    ROW_G(base + 8, 7,  8,9,10,0,1,2,3,4,5,6);
    ROW_G(base + 9, 8,  9,10,0,1,2,3,4,5,6,7);
    ROW_G(base + 10, 9, 10,0,1,2,3,4,5,6,7,8);
  }
  return sum;
}

// ---------------- safe path (branch-free, reordered) ----------------
#define SLD(K) \
  const float p##K = rpl_[K]; const float t##K = rtl_[K];

#define SDS(PC, TC) \
    if (DS) { \
      if (r_ < y0 + nout) { \
        if ((r_ & 1) == 0) { pr = (PC); tr = (TC); } \
        else { \
          float sp_ = pr + (PC), st_ = tr + (TC); \
          sp_ += __shfl_xor(sp_, 1, 64); \
          st_ += __shfl_xor(st_, 1, 64); \
          if ((lane & 1) == 0) { \
            const size_t o_ = obase + (size_t)(r_ >> 1) * (size_t)(W >> 1) + \
                              (size_t)(gx >> 1); \
            dsP[o_] = sp_ * 0.25f; \
            dsT[o_] = st_ * 0.25f; \
          } } } }

// Prologue row RR -> slot SW (rows all in-bounds; ds rows y0.. only).
#define SPRO(RR, SW) do { \
    const int r_ = (RR); \
    const float* rpl_ = Pi + (size_t)r_ * W + gx - 5; \
    const float* rtl_ = Ti + (size_t)r_ * W + gx - 5; \
    FOR11(SLD) \
    float hA_ = 0.f, hB_ = 0.f, hP_ = 0.f, hQ_ = 0.f; \
    FOR11(HACC) \
    rA##SW = hA_; rB##SW = hB_; rP##SW = hP_; rQ##SW = hQ_; \
    if (r_ >= y0) { SDS(p5, t5) } \
  } while (0)

// Body j: load row y0+5+j -> v-conv output j-1 over S0..S10 (rows j-6..j+4,
// independent of the in-flight loads) -> h-conv into S0 (dead slot).
#define ROW_S(JJ, S0,S1,S2,S3,S4,S5,S6,S7,S8,S9,S10) do { \
    const int i_ = base + (JJ); \
    const int r_ = y0 + 5 + i_; \
    const float* rpl_ = Pi + (size_t)r_ * W + gx - 5; \
    const float* rtl_ = Ti + (size_t)r_ * W + gx - 5; \
    FOR11(SLD) \
    float vA_ = G0 * rA##S0, vB_ = G0 * rB##S0; \
    float vP_ = G0 * rP##S0, vQ_ = G0 * rQ##S0; \
    VSTEP(G1, S1) VSTEP(G2, S2) VSTEP(G3, S3) VSTEP(G4, S4) VSTEP(G5, S5) \
    VSTEP(G6, S6) VSTEP(G7, S7) VSTEP(G8, S8) VSTEP(G9, S9) VSTEP(G10, S10) \
    SSIM_STATS \
    if ((i_ >= 1) && (i_ - 1 < nout)) sum += val_; \
    float hA_ = 0.f, hB_ = 0.f, hP_ = 0.f, hQ_ = 0.f; \
    FOR11(HACC) \
    rA##S0 = hA_; rB##S0 = hB_; rP##S0 = hP_; rQ##S0 = hQ_; \
    SDS(p5, t5) \
  } while (0)

template <int DS, int LAST>
__device__ __forceinline__ float strip_safe(
    const float* __restrict__ Pi, const float* __restrict__ Ti,
    const int H, const int W, const int y0, const int nout, const int c0,
    float* __restrict__ dsP, float* __restrict__ dsT, const size_t obase,
    const float G0, const float G1, const float G2, const float G3,
    const float G4, const float G5, const float G6, const float G7,
    const float G8, const float G9, const float G10) {
  const int lane = threadIdx.x & 63;
  const int gx = c0 + lane;
  FOR11(DECLR)
  float pr = 0.f, tr = 0.f, sum = 0.f;

  // Slot 0 = zeros (virtual row y0-6; feeds only discarded output -1).
  SPRO(y0 - 5, 1); SPRO(y0 - 4, 2); SPRO(y0 - 3, 3); SPRO(y0 - 2, 4);
  SPRO(y0 - 1, 5); SPRO(y0 + 0, 6); SPRO(y0 + 1, 7); SPRO(y0 + 2, 8);
  SPRO(y0 + 3, 9); SPRO(y0 + 4, 10);

  for (int base = 0; base < nout + 1; base += 11) {
    ROW_S(0,  0,1,2,3,4,5,6,7,8,9,10);
    ROW_S(1,  1,2,3,4,5,6,7,8,9,10,0);
    ROW_S(2,  2,3,4,5,6,7,8,9,10,0,1);
    ROW_S(3,  3,4,5,6,7,8,9,10,0,1,2);
    ROW_S(4,  4,5,6,7,8,9,10,0,1,2,3);
    ROW_S(5,  5,6,7,8,9,10,0,1,2,3,4);
    ROW_S(6,  6,7,8,9,10,0,1,2,3,4,5);
    ROW_S(7,  7,8,9,10,0,1,2,3,4,5,6);
    ROW_S(8,  8,9,10,0,1,2,3,4,5,6,7);
    ROW_S(9,  9,10,0,1,2,3,4,5,6,7,8);
    ROW_S(10, 10,0,1,2,3,4,5,6,7,8,9);
  }
  return sum;
}

template <int DS, int LAST>
__global__ __launch_bounds__(256, 3)
void msssim_level_k(const float* __restrict__ P, const float* __restrict__ T,
                    const int H, const int W, const int strips,
                    const int chunks, const int chunkH, const int tasks,
                    float* __restrict__ dsP, float* __restrict__ dsT,
                    double* __restrict__ partial,
                    const float G0, const float G1, const float G2,
                    const float G3, const float G4, const float G5,
                    const float G6, const float G7, const float G8,
                    const float G9, const float G10) {
  __shared__ float sRed[4];
  const int tid = threadIdx.x;
  const int lane = tid & 63;
  const int wid = tid >> 6;
  float sum = 0.f;
  const int task = blockIdx.x * 4 + wid;
  if (task < tasks) {
    const int strip = task % strips;
    const int rem = task / strips;
    const int chunk = rem % chunks;
    const int img = rem / chunks;
    const int y0 = chunk * chunkH;
    const int nout = min(chunkH, H - y0);
    const size_t ibase = (size_t)img * H * W;
    const size_t obase = DS ? (size_t)img * (size_t)(H >> 1) * (W >> 1) : 0;
    const bool edgeS = (strip == 0) || (strip * 64 + 69 > W);
    const int nbodies = ((nout + 11) / 11) * 11;           // bodies in safe loop
    const bool safeR = (y0 >= 5) && (y0 + 5 + nbodies - 1 < H);
    if (!edgeS && safeR)
      sum = strip_safe<DS, LAST>(P + ibase, T + ibase, H, W, y0, nout,
                                 strip * 64, dsP, dsT, obase,
                                 G0, G1, G2, G3, G4, G5, G6, G7, G8, G9, G10);
    else if (!edgeS)
      sum = strip_guard<0, DS, LAST>(P + ibase, T + ibase, H, W, y0, nout,
                                     strip * 64, dsP, dsT, obase,
                                     G0, G1, G2, G3, G4, G5, G6, G7, G8, G9, G10);
    else
      sum = strip_guard<1, DS, LAST>(P + ibase, T + ibase, H, W, y0, nout,
                                     strip * 64, dsP, dsT, obase,
                                     G0, G1, G2, G3, G4, G5, G6, G7, G8, G9, G10);
  }
#pragma unroll
  for (int off = 32; off; off >>= 1) sum += __shfl_down(sum, off, 64);
  if (lane == 0) sRed[wid] = sum;
  __syncthreads();
  if (tid == 0)
    partial[blockIdx.x] = (double)(sRed[0] + sRed[1] + sRed[2] + sRed[3]);
}

__global__ void msssim_combine_k(const double* __restrict__ partial,
                                 float* __restrict__ out, const CInfo ci) {
  const int lane = threadIdx.x & 63;
  double lv[5];
#pragma unroll
  for (int L = 0; L < 5; ++L) {
    double s = 0.0;
    for (int i = lane; i < ci.cnt[L]; i += 64) s += partial[ci.base[L] + i];
#pragma unroll
    for (int off = 32; off; off >>= 1) s += __shfl_down(s, off, 64);
    lv[L] = s;
  }
  if (lane == 0) {
    double ms = lv[4] / (48.0 * 32.0 * 32.0);
    ms *= pow(lv[0] / (48.0 * 512.0 * 512.0), (double)0.0448f);
    ms *= pow(lv[1] / (48.0 * 256.0 * 256.0), (double)0.2856f);
    ms *= pow(lv[2] / (48.0 * 128.0 * 128.0), (double)0.3001f);
    ms *= pow(lv[3] / (48.0 * 64.0 * 64.0),  (double)0.2363f);
    out[0] = (float)(1.0 - ms);
  }
}

extern "C" void kernel_launch(void* const* d_in, const int* in_sizes, int n_in,
                              void* d_out, int out_size, void* d_ws, size_t ws_size,
                              hipStream_t stream) {
  const float* pred = (const float*)d_in[0];
  const float* targ = (const float*)d_in[1];
  float* out = (float*)d_out;

  char* ws = (char*)d_ws;
  double* partial = (double*)ws;  // per-block partial sums, 32KB region
  size_t off = 32768;
  auto alloc = [&](size_t elems) {
    float* p = (float*)(ws + off);
    off += elems * sizeof(float);
    return p;
  };
  float* L1p = alloc((size_t)NIMG * 256 * 256);
  float* L1t = alloc((size_t)NIMG * 256 * 256);
  float* L2p = alloc((size_t)NIMG * 128 * 128);
  float* L2t = alloc((size_t)NIMG * 128 * 128);
  float* L3p = alloc((size_t)NIMG * 64 * 64);
  float* L3t = alloc((size_t)NIMG * 64 * 64);
  float* L4p = alloc((size_t)NIMG * 32 * 32);
  float* L4t = alloc((size_t)NIMG * 32 * 32);

  float g[11];
  {
    double gd[11], s = 0.0;
    for (int k = 0; k < 11; ++k) {
      const double c = (double)(k - 5);
      gd[k] = exp(-(c * c) / 4.5);  // 2*sigma^2 = 4.5
      s += gd[k];
    }
    for (int k = 0; k < 11; ++k) g[k] = (float)(gd[k] / s);
  }

  CInfo ci;
  int slotOff = 0;

  auto launchLevel = [&](const float* P, const float* T, int H, int W,
                         int chunkH, float* dP, float* dT, int L, bool last) {
    const int strips = (W + 63) / 64;
    const int chunks = (H + chunkH - 1) / chunkH;
    const int tasks = strips * chunks * NIMG;
    const int blocks = (tasks + 3) / 4;
    ci.base[L] = slotOff;
    ci.cnt[L] = blocks;
    if (last) {
      msssim_level_k<0, 1><<<blocks, 256, 0, stream>>>(
          P, T, H, W, strips, chunks, chunkH, tasks, nullptr, nullptr,
          partial + slotOff, g[0], g[1], g[2], g[3], g[4], g[5], g[6], g[7],
          g[8], g[9], g[10]);
    } else {
      msssim_level_k<1, 0><<<blocks, 256, 0, stream>>>(
          P, T, H, W, strips, chunks, chunkH, tasks, dP, dT,
          partial + slotOff, g[0], g[1], g[2], g[3], g[4], g[5], g[6], g[7],
          g[8], g[9], g[10]);
    }
    slotOff += blocks;
  };

  launchLevel(pred, targ, 512, 512, 64, L1p, L1t, 0, false);
  launchLevel(L1p, L1t, 256, 256, 64, L2p, L2t, 1, false);
  launchLevel(L2p, L2t, 128, 128, 64, L3p, L3t, 2, false);
  launchLevel(L3p, L3t, 64, 64, 64, L4p, L4t, 3, false);
  launchLevel(L4p, L4t, 32, 32, 32, nullptr, nullptr, 4, true);

  msssim_combine_k<<<1, 64, 0, stream>>>(partial, out, ci);
}

// Round 13
// 527.707 us; speedup vs baseline: 1.8829x; 1.0688x over previous
//
#include <hip/hip_runtime.h>
#include <math.h>

// MS-SSIM loss, 5 levels, 11x11 separable Gaussian, zero padding.
// R13 = R12 source + ONE lever: __attribute__((amdgpu_waves_per_eu(3,4))).
// Root cause isolated over R2..R12: the backend scheduler targets 6-8
// waves/EU (VGPR_Count always exactly 84 = 512/6 in every failing round) and
// SPILLS to scratch rather than lowering occupancy; launch_bounds' 2nd arg
// is only a minimum so it never raises the register budget. Pinning
// waves-per-eu to [3,4] grants a 128-168 VGPR budget, which the reordered
// safe-path body (~115 live floats: 22 in-flight taps + 44 ring + accs)
// fits. Guarded path (R5 verbatim) handles boundary tasks.

#define NIMG 48            // 16 * 3
#define TWO_C1 2.0e-4f     // 2 * (0.01*1.0)^2
#define TWO_C2 1.8e-3f     // 2 * (0.03*1.0)^2

struct CInfo { int base[5]; int cnt[5]; };

#define FOR11(X) X(0) X(1) X(2) X(3) X(4) X(5) X(6) X(7) X(8) X(9) X(10)

#define DECLR(K) float rA##K = 0.f, rB##K = 0.f, rP##K = 0.f, rQ##K = 0.f;

#define HACC(K) { \
    const float a_ = p##K + t##K; \
    const float b_ = p##K - t##K; \
    hA_ = __builtin_fmaf(G##K, a_, hA_); \
    hB_ = __builtin_fmaf(G##K, b_, hB_); \
    hP_ = __builtin_fmaf(G##K * a_, a_, hP_); \
    hQ_ = __builtin_fmaf(G##K * b_, b_, hQ_); }

#define VSTEP(GK, S) \
    vA_ = __builtin_fmaf(GK, rA##S, vA_); vB_ = __builtin_fmaf(GK, rB##S, vB_); \
    vP_ = __builtin_fmaf(GK, rP##S, vP_); vQ_ = __builtin_fmaf(GK, rQ##S, vQ_);

#define SSIM_STATS \
    const float A2_ = vA_ * vA_, B2_ = vB_ * vB_; \
    const float dAB_ = A2_ - B2_, sAB_ = A2_ + B2_; \
    const float cn_ = (vP_ - vQ_) - dAB_ + TWO_C2; \
    const float cd_ = (vP_ + vQ_) - sAB_ + TWO_C2; \
    float val_; \
    if (LAST) val_ = ((dAB_ + TWO_C1) * cn_) / ((sAB_ + TWO_C1) * cd_); \
    else      val_ = cn_ / cd_;

// ---------------- guarded path (R5 verbatim) ----------------
#define TAPLOAD_I(K) \
  const float p##K = rpl_[K]; const float t##K = rtl_[K];
#define TAPLOAD_M(K) \
  float p##K, t##K; { \
    const int x_ = gx + (K) - 5; \
    const int xc_ = min(max(x_, 0), W - 1); \
    const float pv_ = rp_[xc_], tv_ = rt_[xc_]; \
    const bool ok_ = ((unsigned)x_ < (unsigned)W); \
    p##K = ok_ ? pv_ : 0.f; t##K = ok_ ? tv_ : 0.f; }

#define MS_STEP_N(R, SW) do { \
    const int r_ = (R); \
    float hA_ = 0.f, hB_ = 0.f, hP_ = 0.f, hQ_ = 0.f; \
    float pc_ = 0.f, tc_ = 0.f; \
    if ((unsigned)r_ < (unsigned)H) { \
      const float* rp_ = Pi + (size_t)r_ * W; \
      const float* rt_ = Ti + (size_t)r_ * W; \
      if (MASKED) { \
        FOR11(TAPLOAD_M) \
        FOR11(HACC) \
        pc_ = p5; tc_ = t5; \
      } else { \
        const float* rpl_ = rp_ + gx - 5; \
        const float* rtl_ = rt_ + gx - 5; \
        FOR11(TAPLOAD_I) \
        FOR11(HACC) \
        pc_ = p5; tc_ = t5; \
      } \
    } \
    rA##SW = hA_; rB##SW = hB_; rP##SW = hP_; rQ##SW = hQ_; \
    if (DS) { \
      if (r_ >= y0 && r_ < y0 + nout) { \
        if ((r_ & 1) == 0) { pr = pc_; tr = tc_; } \
        else { \
          float sp_ = pr + pc_, st_ = tr + tc_; \
          sp_ += __shfl_xor(sp_, 1, 64); \
          st_ += __shfl_xor(st_, 1, 64); \
          if (((lane & 1) == 0) && (gx < W)) { \
            const size_t o_ = obase + (size_t)(r_ >> 1) * (size_t)(W >> 1) + \
                              (size_t)(gx >> 1); \
            dsP[o_] = sp_ * 0.25f; \
            dsT[o_] = st_ * 0.25f; \
          } } } } \
  } while (0)

#define ROW_G(IROW, SW, S0,S1,S2,S3,S4,S5,S6,S7,S8,S9) do { \
    const int i_ = (IROW); \
    const bool live_ = (i_ < nout); \
    MS_STEP_N(y0 + 5 + i_, SW); \
    float vA_ = G0 * rA##S0, vB_ = G0 * rB##S0; \
    float vP_ = G0 * rP##S0, vQ_ = G0 * rQ##S0; \
    VSTEP(G1, S1) VSTEP(G2, S2) VSTEP(G3, S3) VSTEP(G4, S4) VSTEP(G5, S5) \
    VSTEP(G6, S6) VSTEP(G7, S7) VSTEP(G8, S8) VSTEP(G9, S9) VSTEP(G10, SW) \
    SSIM_STATS \
    if ((!MASKED || gx < W) && live_) sum += val_; \
  } while (0)

template <int MASKED, int DS, int LAST>
__device__ __forceinline__ float strip_guard(
    const float* __restrict__ Pi, const float* __restrict__ Ti,
    const int H, const int W, const int y0, const int nout, const int c0,
    float* __restrict__ dsP, float* __restrict__ dsT, const size_t obase,
    const float G0, const float G1, const float G2, const float G3,
    const float G4, const float G5, const float G6, const float G7,
    const float G8, const float G9, const float G10) {
  const int lane = threadIdx.x & 63;
  const int gx = c0 + lane;
  FOR11(DECLR)
  float pr = 0.f, tr = 0.f, sum = 0.f;

  MS_STEP_N(y0 - 5, 0); MS_STEP_N(y0 - 4, 1); MS_STEP_N(y0 - 3, 2);
  MS_STEP_N(y0 - 2, 3); MS_STEP_N(y0 - 1, 4); MS_STEP_N(y0 + 0, 5);
  MS_STEP_N(y0 + 1, 6); MS_STEP_N(y0 + 2, 7); MS_STEP_N(y0 + 3, 8);
  MS_STEP_N(y0 + 4, 9);

  for (int base = 0; base < nout; base += 11) {
    ROW_G(base + 0, 10, 0,1,2,3,4,5,6,7,8,9);
    ROW_G(base + 1, 0,  1,2,3,4,5,6,7,8,9,10);
    ROW_G(base + 2, 1,  2,3,4,5,6,7,8,9,10,0);
    ROW_G(base + 3, 2,  3,4,5,6,7,8,9,10,0,1);
    ROW_G(base + 4, 3,  4,5,6,7,8,9,10,0,1,2);
    ROW_G(base + 5, 4,  5,6,7,8,9,10,0,1,2,3);
    ROW_G(base + 6, 5,  6,7,8,9,10,0,1,2,3,4);
    ROW_G(base + 7, 6,  7,8,9,10,0,1,2,3,4,5);
    ROW_G(base + 8, 7,  8,9,10,0,1,2,3,4,5,6);
    ROW_G(base + 9, 8,  9,10,0,1,2,3,4,5,6,7);
    ROW_G(base + 10, 9, 10,0,1,2,3,4,5,6,7,8);
  }
  return sum;
}

// ---------------- safe path (branch-free, reordered) ----------------
#define SLD(K) \
  const float p##K = rpl_[K]; const float t##K = rtl_[K];

#define SDS(PC, TC) \
    if (DS) { \
      if (r_ < y0 + nout) { \
        if ((r_ & 1) == 0) { pr = (PC); tr = (TC); } \
        else { \
          float sp_ = pr + (PC), st_ = tr + (TC); \
          sp_ += __shfl_xor(sp_, 1, 64); \
          st_ += __shfl_xor(st_, 1, 64); \
          if ((lane & 1) == 0) { \
            const size_t o_ = obase + (size_t)(r_ >> 1) * (size_t)(W >> 1) + \
                              (size_t)(gx >> 1); \
            dsP[o_] = sp_ * 0.25f; \
            dsT[o_] = st_ * 0.25f; \
          } } } }

#define SPRO(RR, SW) do { \
    const int r_ = (RR); \
    const float* rpl_ = Pi + (size_t)r_ * W + gx - 5; \
    const float* rtl_ = Ti + (size_t)r_ * W + gx - 5; \
    FOR11(SLD) \
    float hA_ = 0.f, hB_ = 0.f, hP_ = 0.f, hQ_ = 0.f; \
    FOR11(HACC) \
    rA##SW = hA_; rB##SW = hB_; rP##SW = hP_; rQ##SW = hQ_; \
    if (r_ >= y0) { SDS(p5, t5) } \
  } while (0)

#define ROW_S(JJ, S0,S1,S2,S3,S4,S5,S6,S7,S8,S9,S10) do { \
    const int i_ = base + (JJ); \
    const int r_ = y0 + 5 + i_; \
    const float* rpl_ = Pi + (size_t)r_ * W + gx - 5; \
    const float* rtl_ = Ti + (size_t)r_ * W + gx - 5; \
    FOR11(SLD) \
    float vA_ = G0 * rA##S0, vB_ = G0 * rB##S0; \
    float vP_ = G0 * rP##S0, vQ_ = G0 * rQ##S0; \
    VSTEP(G1, S1) VSTEP(G2, S2) VSTEP(G3, S3) VSTEP(G4, S4) VSTEP(G5, S5) \
    VSTEP(G6, S6) VSTEP(G7, S7) VSTEP(G8, S8) VSTEP(G9, S9) VSTEP(G10, S10) \
    SSIM_STATS \
    if ((i_ >= 1) && (i_ - 1 < nout)) sum += val_; \
    float hA_ = 0.f, hB_ = 0.f, hP_ = 0.f, hQ_ = 0.f; \
    FOR11(HACC) \
    rA##S0 = hA_; rB##S0 = hB_; rP##S0 = hP_; rQ##S0 = hQ_; \
    SDS(p5, t5) \
  } while (0)

template <int DS, int LAST>
__device__ __forceinline__ float strip_safe(
    const float* __restrict__ Pi, const float* __restrict__ Ti,
    const int H, const int W, const int y0, const int nout, const int c0,
    float* __restrict__ dsP, float* __restrict__ dsT, const size_t obase,
    const float G0, const float G1, const float G2, const float G3,
    const float G4, const float G5, const float G6, const float G7,
    const float G8, const float G9, const float G10) {
  const int lane = threadIdx.x & 63;
  const int gx = c0 + lane;
  FOR11(DECLR)
  float pr = 0.f, tr = 0.f, sum = 0.f;

  SPRO(y0 - 5, 1); SPRO(y0 - 4, 2); SPRO(y0 - 3, 3); SPRO(y0 - 2, 4);
  SPRO(y0 - 1, 5); SPRO(y0 + 0, 6); SPRO(y0 + 1, 7); SPRO(y0 + 2, 8);
  SPRO(y0 + 3, 9); SPRO(y0 + 4, 10);

  for (int base = 0; base < nout + 1; base += 11) {
    ROW_S(0,  0,1,2,3,4,5,6,7,8,9,10);
    ROW_S(1,  1,2,3,4,5,6,7,8,9,10,0);
    ROW_S(2,  2,3,4,5,6,7,8,9,10,0,1);
    ROW_S(3,  3,4,5,6,7,8,9,10,0,1,2);
    ROW_S(4,  4,5,6,7,8,9,10,0,1,2,3);
    ROW_S(5,  5,6,7,8,9,10,0,1,2,3,4);
    ROW_S(6,  6,7,8,9,10,0,1,2,3,4,5);
    ROW_S(7,  7,8,9,10,0,1,2,3,4,5,6);
    ROW_S(8,  8,9,10,0,1,2,3,4,5,6,7);
    ROW_S(9,  9,10,0,1,2,3,4,5,6,7,8);
    ROW_S(10, 10,0,1,2,3,4,5,6,7,8,9);
  }
  return sum;
}

template <int DS, int LAST>
__global__ __launch_bounds__(256)
__attribute__((amdgpu_waves_per_eu(3, 4)))
void msssim_level_k(const float* __restrict__ P, const float* __restrict__ T,
                    const int H, const int W, const int strips,
                    const int chunks, const int chunkH, const int tasks,
                    float* __restrict__ dsP, float* __restrict__ dsT,
                    double* __restrict__ partial,
                    const float G0, const float G1, const float G2,
                    const float G3, const float G4, const float G5,
                    const float G6, const float G7, const float G8,
                    const float G9, const float G10) {
  __shared__ float sRed[4];
  const int tid = threadIdx.x;
  const int lane = tid & 63;
  const int wid = tid >> 6;
  float sum = 0.f;
  const int task = blockIdx.x * 4 + wid;
  if (task < tasks) {
    const int strip = task % strips;
    const int rem = task / strips;
    const int chunk = rem % chunks;
    const int img = rem / chunks;
    const int y0 = chunk * chunkH;
    const int nout = min(chunkH, H - y0);
    const size_t ibase = (size_t)img * H * W;
    const size_t obase = DS ? (size_t)img * (size_t)(H >> 1) * (W >> 1) : 0;
    const bool edgeS = (strip == 0) || (strip * 64 + 69 > W);
    const int nbodies = ((nout + 11) / 11) * 11;
    const bool safeR = (y0 >= 5) && (y0 + 5 + nbodies - 1 < H);
    if (!edgeS && safeR)
      sum = strip_safe<DS, LAST>(P + ibase, T + ibase, H, W, y0, nout,
                                 strip * 64, dsP, dsT, obase,
                                 G0, G1, G2, G3, G4, G5, G6, G7, G8, G9, G10);
    else if (!edgeS)
      sum = strip_guard<0, DS, LAST>(P + ibase, T + ibase, H, W, y0, nout,
                                     strip * 64, dsP, dsT, obase,
                                     G0, G1, G2, G3, G4, G5, G6, G7, G8, G9, G10);
    else
      sum = strip_guard<1, DS, LAST>(P + ibase, T + ibase, H, W, y0, nout,
                                     strip * 64, dsP, dsT, obase,
                                     G0, G1, G2, G3, G4, G5, G6, G7, G8, G9, G10);
  }
#pragma unroll
  for (int off = 32; off; off >>= 1) sum += __shfl_down(sum, off, 64);
  if (lane == 0) sRed[wid] = sum;
  __syncthreads();
  if (tid == 0)
    partial[blockIdx.x] = (double)(sRed[0] + sRed[1] + sRed[2] + sRed[3]);
}

__global__ void msssim_combine_k(const double* __restrict__ partial,
                                 float* __restrict__ out, const CInfo ci) {
  const int lane = threadIdx.x & 63;
  double lv[5];
#pragma unroll
  for (int L = 0; L < 5; ++L) {
    double s = 0.0;
    for (int i = lane; i < ci.cnt[L]; i += 64) s += partial[ci.base[L] + i];
#pragma unroll
    for (int off = 32; off; off >>= 1) s += __shfl_down(s, off, 64);
    lv[L] = s;
  }
  if (lane == 0) {
    double ms = lv[4] / (48.0 * 32.0 * 32.0);
    ms *= pow(lv[0] / (48.0 * 512.0 * 512.0), (double)0.0448f);
    ms *= pow(lv[1] / (48.0 * 256.0 * 256.0), (double)0.2856f);
    ms *= pow(lv[2] / (48.0 * 128.0 * 128.0), (double)0.3001f);
    ms *= pow(lv[3] / (48.0 * 64.0 * 64.0),  (double)0.2363f);
    out[0] = (float)(1.0 - ms);
  }
}

extern "C" void kernel_launch(void* const* d_in, const int* in_sizes, int n_in,
                              void* d_out, int out_size, void* d_ws, size_t ws_size,
                              hipStream_t stream) {
  const float* pred = (const float*)d_in[0];
  const float* targ = (const float*)d_in[1];
  float* out = (float*)d_out;

  char* ws = (char*)d_ws;
  double* partial = (double*)ws;  // per-block partial sums, 32KB region
  size_t off = 32768;
  auto alloc = [&](size_t elems) {
    float* p = (float*)(ws + off);
    off += elems * sizeof(float);
    return p;
  };
  float* L1p = alloc((size_t)NIMG * 256 * 256);
  float* L1t = alloc((size_t)NIMG * 256 * 256);
  float* L2p = alloc((size_t)NIMG * 128 * 128);
  float* L2t = alloc((size_t)NIMG * 128 * 128);
  float* L3p = alloc((size_t)NIMG * 64 * 64);
  float* L3t = alloc((size_t)NIMG * 64 * 64);
  float* L4p = alloc((size_t)NIMG * 32 * 32);
  float* L4t = alloc((size_t)NIMG * 32 * 32);

  float g[11];
  {
    double gd[11], s = 0.0;
    for (int k = 0; k < 11; ++k) {
      const double c = (double)(k - 5);
      gd[k] = exp(-(c * c) / 4.5);  // 2*sigma^2 = 4.5
      s += gd[k];
    }
    for (int k = 0; k < 11; ++k) g[k] = (float)(gd[k] / s);
  }

  CInfo ci;
  int slotOff = 0;

  auto launchLevel = [&](const float* P, const float* T, int H, int W,
                         int chunkH, float* dP, float* dT, int L, bool last) {
    const int strips = (W + 63) / 64;
    const int chunks = (H + chunkH - 1) / chunkH;
    const int tasks = strips * chunks * NIMG;
    const int blocks = (tasks + 3) / 4;
    ci.base[L] = slotOff;
    ci.cnt[L] = blocks;
    if (last) {
      msssim_level_k<0, 1><<<blocks, 256, 0, stream>>>(
          P, T, H, W, strips, chunks, chunkH, tasks, nullptr, nullptr,
          partial + slotOff, g[0], g[1], g[2], g[3], g[4], g[5], g[6], g[7],
          g[8], g[9], g[10]);
    } else {
      msssim_level_k<1, 0><<<blocks, 256, 0, stream>>>(
          P, T, H, W, strips, chunks, chunkH, tasks, dP, dT,
          partial + slotOff, g[0], g[1], g[2], g[3], g[4], g[5], g[6], g[7],
          g[8], g[9], g[10]);
    }
    slotOff += blocks;
  };

  launchLevel(pred, targ, 512, 512, 64, L1p, L1t, 0, false);
  launchLevel(L1p, L1t, 256, 256, 64, L2p, L2t, 1, false);
  launchLevel(L2p, L2t, 128, 128, 64, L3p, L3t, 2, false);
  launchLevel(L3p, L3t, 64, 64, 16, L4p, L4t, 3, false);
  launchLevel(L4p, L4t, 32, 32, 8, nullptr, nullptr, 4, true);

  msssim_combine_k<<<1, 64, 0, stream>>>(partial, out, ci);
}

// Round 14
// 200.477 us; speedup vs baseline: 4.9564x; 2.6323x over previous
//
#include <hip/hip_runtime.h>
#include <math.h>

// MS-SSIM loss, 5 levels, 11x11 separable Gaussian, zero padding.
// R14 = R5 device code (the only verified scratch-free structure) with:
//   (1) __launch_bounds__(256) -- the ",3" min-waves dropped. Evidence: every
//       spill event (R2..R13, VGPR pinned at 84, 100s of MB scratch) had an
//       explicit waves bound; R1 with plain (256) got 236 VGPRs, no scratch.
//       Without the bound the scheduler may hoist loads with a full budget.
//   (2) launcher-only fill fixes for the pyramid tail: L2 CH 32->8 (96->384
//       blocks), L3 CH 16->8 (48->96 blocks). L0/L1 unchanged.

#define NIMG 48            // 16 * 3
#define TWO_C1 2.0e-4f     // 2 * (0.01*1.0)^2
#define TWO_C2 1.8e-3f     // 2 * (0.03*1.0)^2

struct CInfo { int base[5]; int cnt[5]; };

#define FOR11(X) X(0) X(1) X(2) X(3) X(4) X(5) X(6) X(7) X(8) X(9) X(10)

// --- tap loads: declare p0..p10, t0..t10 as named scalars ---
#define TAPLOAD_I(K) \
  const float p##K = rpl_[K]; const float t##K = rtl_[K];
#define TAPLOAD_M(K) \
  float p##K, t##K; { \
    const int x_ = gx + (K) - 5; \
    const int xc_ = min(max(x_, 0), W - 1); \
    const float pv_ = rp_[xc_], tv_ = rt_[xc_]; \
    const bool ok_ = ((unsigned)x_ < (unsigned)W); \
    p##K = ok_ ? pv_ : 0.f; t##K = ok_ ? tv_ : 0.f; }

// --- horizontal accumulate over taps ---
#define HACC(K) { \
    const float a_ = p##K + t##K, b_ = p##K - t##K; \
    hA_ = __builtin_fmaf(G##K, a_, hA_); \
    hB_ = __builtin_fmaf(G##K, b_, hB_); \
    hP_ = __builtin_fmaf(G##K * a_, a_, hP_); \
    hQ_ = __builtin_fmaf(G##K * b_, b_, hQ_); }

// --- ring scalar declarations ---
#define DECLR(K) float rA##K = 0.f, rB##K = 0.f, rP##K = 0.f, rQ##K = 0.f;

// One input row R: load taps, horizontal conv into ring slot SW (literal),
// fused 2x2 avg-pool on center taps.
#define MS_STEP_N(R, SW) do { \
    const int r_ = (R); \
    float hA_ = 0.f, hB_ = 0.f, hP_ = 0.f, hQ_ = 0.f; \
    float pc_ = 0.f, tc_ = 0.f; \
    if ((unsigned)r_ < (unsigned)H) { \
      const float* rp_ = Pi + (size_t)r_ * W; \
      const float* rt_ = Ti + (size_t)r_ * W; \
      if (MASKED) { \
        FOR11(TAPLOAD_M) \
        FOR11(HACC) \
        pc_ = p5; tc_ = t5; \
      } else { \
        const float* rpl_ = rp_ + gx - 5; \
        const float* rtl_ = rt_ + gx - 5; \
        FOR11(TAPLOAD_I) \
        FOR11(HACC) \
        pc_ = p5; tc_ = t5; \
      } \
    } \
    rA##SW = hA_; rB##SW = hB_; rP##SW = hP_; rQ##SW = hQ_; \
    if (DS) { \
      if (r_ >= y0 && r_ < y0 + nout) { \
        if ((r_ & 1) == 0) { pr = pc_; tr = tc_; } \
        else { \
          float sp_ = pr + pc_, st_ = tr + tc_; \
          sp_ += __shfl_xor(sp_, 1, 64); \
          st_ += __shfl_xor(st_, 1, 64); \
          if (((lane & 1) == 0) && (gx < W)) { \
            const size_t o_ = obase + (size_t)(r_ >> 1) * (size_t)(W >> 1) + \
                              (size_t)(gx >> 1); \
            dsP[o_] = sp_ * 0.25f; \
            dsT[o_] = st_ * 0.25f; \
          } } } } \
  } while (0)

#define VSTEP(GK, S) \
    A_ = __builtin_fmaf(GK, rA##S, A_); B_ = __builtin_fmaf(GK, rB##S, B_); \
    P_ = __builtin_fmaf(GK, rP##S, P_); Q_ = __builtin_fmaf(GK, rQ##S, Q_);

// One output row. SW/S0..S10 are literal slot numbers; S_k holds row (i-5+k).
#define ROW_N(IROW, SW, S0,S1,S2,S3,S4,S5,S6,S7,S8,S9,S10) do { \
    const int i_ = (IROW); \
    const bool live_ = (i_ < nout); \
    MS_STEP_N(y0 + 5 + i_, SW); \
    float A_ = G0 * rA##S0, B_ = G0 * rB##S0; \
    float P_ = G0 * rP##S0, Q_ = G0 * rQ##S0; \
    VSTEP(G1, S1) VSTEP(G2, S2) VSTEP(G3, S3) VSTEP(G4, S4) VSTEP(G5, S5) \
    VSTEP(G6, S6) VSTEP(G7, S7) VSTEP(G8, S8) VSTEP(G9, S9) VSTEP(G10, S10) \
    const float A2_ = A_ * A_, B2_ = B_ * B_; \
    const float dAB_ = A2_ - B2_, sAB_ = A2_ + B2_; \
    const float cn_ = (P_ - Q_) - dAB_ + TWO_C2; \
    const float cd_ = (P_ + Q_) - sAB_ + TWO_C2; \
    float val_; \
    if (LAST) val_ = ((dAB_ + TWO_C1) * cn_) / ((sAB_ + TWO_C1) * cd_); \
    else      val_ = cn_ / cd_; \
    if ((!MASKED || gx < W) && live_) sum += val_; \
  } while (0)

template <int MASKED, int DS, int LAST>
__device__ __forceinline__ float strip_run(
    const float* __restrict__ Pi, const float* __restrict__ Ti,
    const int H, const int W, const int y0, const int nout, const int c0,
    float* __restrict__ dsP, float* __restrict__ dsT, const size_t obase,
    const float G0, const float G1, const float G2, const float G3,
    const float G4, const float G5, const float G6, const float G7,
    const float G8, const float G9, const float G10) {
  const int lane = threadIdx.x & 63;
  const int gx = c0 + lane;
  FOR11(DECLR)                       // rA0..rQ10, all named scalars
  float pr = 0.f, tr = 0.f, sum = 0.f;

  // Prologue: slots 0..9 <- rows y0-5 .. y0+4.
  MS_STEP_N(y0 - 5, 0); MS_STEP_N(y0 - 4, 1); MS_STEP_N(y0 - 3, 2);
  MS_STEP_N(y0 - 2, 3); MS_STEP_N(y0 - 1, 4); MS_STEP_N(y0 + 0, 5);
  MS_STEP_N(y0 + 1, 6); MS_STEP_N(y0 + 2, 7); MS_STEP_N(y0 + 3, 8);
  MS_STEP_N(y0 + 4, 9);

  // Main: 11 phases per iteration; slot lists rotate by one each phase.
  for (int base = 0; base < nout; base += 11) {
    ROW_N(base + 0, 10, 0,1,2,3,4,5,6,7,8,9,10);
    ROW_N(base + 1, 0,  1,2,3,4,5,6,7,8,9,10,0);
    ROW_N(base + 2, 1,  2,3,4,5,6,7,8,9,10,0,1);
    ROW_N(base + 3, 2,  3,4,5,6,7,8,9,10,0,1,2);
    ROW_N(base + 4, 3,  4,5,6,7,8,9,10,0,1,2,3);
    ROW_N(base + 5, 4,  5,6,7,8,9,10,0,1,2,3,4);
    ROW_N(base + 6, 5,  6,7,8,9,10,0,1,2,3,4,5);
    ROW_N(base + 7, 6,  7,8,9,10,0,1,2,3,4,5,6);
    ROW_N(base + 8, 7,  8,9,10,0,1,2,3,4,5,6,7);
    ROW_N(base + 9, 8,  9,10,0,1,2,3,4,5,6,7,8);
    ROW_N(base + 10, 9, 10,0,1,2,3,4,5,6,7,8,9);
  }
  return sum;
}

template <int DS, int LAST>
__global__ __launch_bounds__(256)
void msssim_level_k(const float* __restrict__ P, const float* __restrict__ T,
                    const int H, const int W, const int strips,
                    const int chunks, const int chunkH, const int tasks,
                    float* __restrict__ dsP, float* __restrict__ dsT,
                    double* __restrict__ partial,
                    const float G0, const float G1, const float G2,
                    const float G3, const float G4, const float G5,
                    const float G6, const float G7, const float G8,
                    const float G9, const float G10) {
  __shared__ float sRed[4];
  const int tid = threadIdx.x;
  const int lane = tid & 63;
  const int wid = tid >> 6;
  float sum = 0.f;
  const int task = blockIdx.x * 4 + wid;
  if (task < tasks) {
    const int strip = task % strips;
    const int rem = task / strips;
    const int chunk = rem % chunks;
    const int img = rem / chunks;
    const int y0 = chunk * chunkH;
    const int nout = min(chunkH, H - y0);
    const size_t ibase = (size_t)img * H * W;
    const size_t obase = DS ? (size_t)img * (size_t)(H >> 1) * (W >> 1) : 0;
    const bool edge = (strip == 0) || (strip * 64 + 69 > W);  // wave-uniform
    if (edge)
      sum = strip_run<1, DS, LAST>(P + ibase, T + ibase, H, W, y0, nout,
                                   strip * 64, dsP, dsT, obase,
                                   G0, G1, G2, G3, G4, G5, G6, G7, G8, G9, G10);
    else
      sum = strip_run<0, DS, LAST>(P + ibase, T + ibase, H, W, y0, nout,
                                   strip * 64, dsP, dsT, obase,
                                   G0, G1, G2, G3, G4, G5, G6, G7, G8, G9, G10);
  }
#pragma unroll
  for (int off = 32; off; off >>= 1) sum += __shfl_down(sum, off, 64);
  if (lane == 0) sRed[wid] = sum;
  __syncthreads();
  if (tid == 0)
    partial[blockIdx.x] = (double)(sRed[0] + sRed[1] + sRed[2] + sRed[3]);
}

__global__ void msssim_combine_k(const double* __restrict__ partial,
                                 float* __restrict__ out, const CInfo ci) {
  const int lane = threadIdx.x & 63;
  double lv[5];
#pragma unroll
  for (int L = 0; L < 5; ++L) {
    double s = 0.0;
    for (int i = lane; i < ci.cnt[L]; i += 64) s += partial[ci.base[L] + i];
#pragma unroll
    for (int off = 32; off; off >>= 1) s += __shfl_down(s, off, 64);
    lv[L] = s;
  }
  if (lane == 0) {
    double ms = lv[4] / (48.0 * 32.0 * 32.0);
    ms *= pow(lv[0] / (48.0 * 512.0 * 512.0), (double)0.0448f);
    ms *= pow(lv[1] / (48.0 * 256.0 * 256.0), (double)0.2856f);
    ms *= pow(lv[2] / (48.0 * 128.0 * 128.0), (double)0.3001f);
    ms *= pow(lv[3] / (48.0 * 64.0 * 64.0),  (double)0.2363f);
    out[0] = (float)(1.0 - ms);
  }
}

extern "C" void kernel_launch(void* const* d_in, const int* in_sizes, int n_in,
                              void* d_out, int out_size, void* d_ws, size_t ws_size,
                              hipStream_t stream) {
  const float* pred = (const float*)d_in[0];
  const float* targ = (const float*)d_in[1];
  float* out = (float*)d_out;

  char* ws = (char*)d_ws;
  double* partial = (double*)ws;  // per-block partial sums, 32KB region
  size_t off = 32768;
  auto alloc = [&](size_t elems) {
    float* p = (float*)(ws + off);
    off += elems * sizeof(float);
    return p;
  };
  float* L1p = alloc((size_t)NIMG * 256 * 256);
  float* L1t = alloc((size_t)NIMG * 256 * 256);
  float* L2p = alloc((size_t)NIMG * 128 * 128);
  float* L2t = alloc((size_t)NIMG * 128 * 128);
  float* L3p = alloc((size_t)NIMG * 64 * 64);
  float* L3t = alloc((size_t)NIMG * 64 * 64);
  float* L4p = alloc((size_t)NIMG * 32 * 32);
  float* L4t = alloc((size_t)NIMG * 32 * 32);

  float g[11];
  {
    double gd[11], s = 0.0;
    for (int k = 0; k < 11; ++k) {
      const double c = (double)(k - 5);
      gd[k] = exp(-(c * c) / 4.5);  // 2*sigma^2 = 4.5
      s += gd[k];
    }
    for (int k = 0; k < 11; ++k) g[k] = (float)(gd[k] / s);
  }

  CInfo ci;
  int slotOff = 0;

  auto launchLevel = [&](const float* P, const float* T, int H, int W,
                         int chunkH, float* dP, float* dT, int L, bool last) {
    const int strips = (W + 63) / 64;
    const int chunks = (H + chunkH - 1) / chunkH;
    const int tasks = strips * chunks * NIMG;
    const int blocks = (tasks + 3) / 4;
    ci.base[L] = slotOff;
    ci.cnt[L] = blocks;
    if (last) {
      msssim_level_k<0, 1><<<blocks, 256, 0, stream>>>(
          P, T, H, W, strips, chunks, chunkH, tasks, nullptr, nullptr,
          partial + slotOff, g[0], g[1], g[2], g[3], g[4], g[5], g[6], g[7],
          g[8], g[9], g[10]);
    } else {
      msssim_level_k<1, 0><<<blocks, 256, 0, stream>>>(
          P, T, H, W, strips, chunks, chunkH, tasks, dP, dT,
          partial + slotOff, g[0], g[1], g[2], g[3], g[4], g[5], g[6], g[7],
          g[8], g[9], g[10]);
    }
    slotOff += blocks;
  };

  launchLevel(pred, targ, 512, 512, 32, L1p, L1t, 0, false);
  launchLevel(L1p, L1t, 256, 256, 32, L2p, L2t, 1, false);
  launchLevel(L2p, L2t, 128, 128, 8, L3p, L3t, 2, false);
  launchLevel(L3p, L3t, 64, 64, 8, L4p, L4t, 3, false);
  launchLevel(L4p, L4t, 32, 32, 8, nullptr, nullptr, 4, true);

  msssim_combine_k<<<1, 64, 0, stream>>>(partial, out, ci);
}

// Round 15
// 184.526 us; speedup vs baseline: 5.3848x; 1.0864x over previous
//
#include <hip/hip_runtime.h>
#include <math.h>

// MS-SSIM loss, 5 levels, 11x11 separable Gaussian, zero padding.
// R15 = R14 structure (verified scratch-free: named-scalar ring, branch-local
// ephemeral taps, plain __launch_bounds__(256)) + two safe levers:
//   (1) h-conv basis change: convolve (p, t, p^2+t^2, p*t) at 7 ops/tap
//       (was (a,b,a^2,b^2) at 8 ops/tap); SSIM terms reconstructed after the
//       v-conv: m=vp*vt, q=vp^2+vt^2, cn=4(vx-m)+2C2, cd=2(vs-q)+2C2,
//       lum=(4m+2C1)/(2q+2C1). Algebraically identical to R14's dAB/sAB form.
//       Stats 10->6 ops. Net ~9% VALU cut per row-step.
//   (2) launcher: L1 chunkH 32->16 (384->768 blocks; L1 was fill-limited at
//       1.5 blocks/CU). L0 stays CH=32; L2-L4 stay CH=8.

#define NIMG 48            // 16 * 3
#define TWO_C1 2.0e-4f     // 2 * (0.01*1.0)^2
#define TWO_C2 1.8e-3f     // 2 * (0.03*1.0)^2

struct CInfo { int base[5]; int cnt[5]; };

#define FOR11(X) X(0) X(1) X(2) X(3) X(4) X(5) X(6) X(7) X(8) X(9) X(10)

// --- tap loads: declare p0..p10, t0..t10 as named scalars ---
#define TAPLOAD_I(K) \
  const float p##K = rpl_[K]; const float t##K = rtl_[K];
#define TAPLOAD_M(K) \
  float p##K, t##K; { \
    const int x_ = gx + (K) - 5; \
    const int xc_ = min(max(x_, 0), W - 1); \
    const float pv_ = rp_[xc_], tv_ = rt_[xc_]; \
    const bool ok_ = ((unsigned)x_ < (unsigned)W); \
    p##K = ok_ ? pv_ : 0.f; t##K = ok_ ? tv_ : 0.f; }

// --- horizontal accumulate: fields (p, t, p^2+t^2, p*t), 7 ops/tap ---
#define HACC(K) { \
    hA_ = __builtin_fmaf(G##K, p##K, hA_); \
    hB_ = __builtin_fmaf(G##K, t##K, hB_); \
    const float u_ = __builtin_fmaf(t##K, t##K, p##K * p##K); \
    hP_ = __builtin_fmaf(G##K, u_, hP_); \
    const float x_ = p##K * t##K; \
    hQ_ = __builtin_fmaf(G##K, x_, hQ_); }

// --- ring scalar declarations ---
#define DECLR(K) float rA##K = 0.f, rB##K = 0.f, rP##K = 0.f, rQ##K = 0.f;

// One input row R: load taps, horizontal conv into ring slot SW (literal),
// fused 2x2 avg-pool on center taps.
#define MS_STEP_N(R, SW) do { \
    const int r_ = (R); \
    float hA_ = 0.f, hB_ = 0.f, hP_ = 0.f, hQ_ = 0.f; \
    float pc_ = 0.f, tc_ = 0.f; \
    if ((unsigned)r_ < (unsigned)H) { \
      const float* rp_ = Pi + (size_t)r_ * W; \
      const float* rt_ = Ti + (size_t)r_ * W; \
      if (MASKED) { \
        FOR11(TAPLOAD_M) \
        FOR11(HACC) \
        pc_ = p5; tc_ = t5; \
      } else { \
        const float* rpl_ = rp_ + gx - 5; \
        const float* rtl_ = rt_ + gx - 5; \
        FOR11(TAPLOAD_I) \
        FOR11(HACC) \
        pc_ = p5; tc_ = t5; \
      } \
    } \
    rA##SW = hA_; rB##SW = hB_; rP##SW = hP_; rQ##SW = hQ_; \
    if (DS) { \
      if (r_ >= y0 && r_ < y0 + nout) { \
        if ((r_ & 1) == 0) { pr = pc_; tr = tc_; } \
        else { \
          float sp_ = pr + pc_, st_ = tr + tc_; \
          sp_ += __shfl_xor(sp_, 1, 64); \
          st_ += __shfl_xor(st_, 1, 64); \
          if (((lane & 1) == 0) && (gx < W)) { \
            const size_t o_ = obase + (size_t)(r_ >> 1) * (size_t)(W >> 1) + \
                              (size_t)(gx >> 1); \
            dsP[o_] = sp_ * 0.25f; \
            dsT[o_] = st_ * 0.25f; \
          } } } } \
  } while (0)

#define VSTEP(GK, S) \
    A_ = __builtin_fmaf(GK, rA##S, A_); B_ = __builtin_fmaf(GK, rB##S, B_); \
    P_ = __builtin_fmaf(GK, rP##S, P_); Q_ = __builtin_fmaf(GK, rQ##S, Q_);

// One output row. SW/S0..S10 are literal slot numbers; S_k holds row (i-5+k).
// After v-conv: A_=mu_p, B_=mu_t, P_=E[p^2+t^2], Q_=E[pt].
#define ROW_N(IROW, SW, S0,S1,S2,S3,S4,S5,S6,S7,S8,S9,S10) do { \
    const int i_ = (IROW); \
    const bool live_ = (i_ < nout); \
    MS_STEP_N(y0 + 5 + i_, SW); \
    float A_ = G0 * rA##S0, B_ = G0 * rB##S0; \
    float P_ = G0 * rP##S0, Q_ = G0 * rQ##S0; \
    VSTEP(G1, S1) VSTEP(G2, S2) VSTEP(G3, S3) VSTEP(G4, S4) VSTEP(G5, S5) \
    VSTEP(G6, S6) VSTEP(G7, S7) VSTEP(G8, S8) VSTEP(G9, S9) VSTEP(G10, S10) \
    const float m_ = A_ * B_; \
    const float q_ = __builtin_fmaf(A_, A_, B_ * B_); \
    const float cn_ = __builtin_fmaf(4.f, Q_ - m_, TWO_C2); \
    const float cd_ = __builtin_fmaf(2.f, P_ - q_, TWO_C2); \
    float val_; \
    if (LAST) { \
      const float ln_ = __builtin_fmaf(4.f, m_, TWO_C1); \
      const float ld_ = __builtin_fmaf(2.f, q_, TWO_C1); \
      val_ = (ln_ * cn_) / (ld_ * cd_); \
    } else { \
      val_ = cn_ / cd_; \
    } \
    if ((!MASKED || gx < W) && live_) sum += val_; \
  } while (0)

template <int MASKED, int DS, int LAST>
__device__ __forceinline__ float strip_run(
    const float* __restrict__ Pi, const float* __restrict__ Ti,
    const int H, const int W, const int y0, const int nout, const int c0,
    float* __restrict__ dsP, float* __restrict__ dsT, const size_t obase,
    const float G0, const float G1, const float G2, const float G3,
    const float G4, const float G5, const float G6, const float G7,
    const float G8, const float G9, const float G10) {
  const int lane = threadIdx.x & 63;
  const int gx = c0 + lane;
  FOR11(DECLR)                       // rA0..rQ10, all named scalars
  float pr = 0.f, tr = 0.f, sum = 0.f;

  // Prologue: slots 0..9 <- rows y0-5 .. y0+4.
  MS_STEP_N(y0 - 5, 0); MS_STEP_N(y0 - 4, 1); MS_STEP_N(y0 - 3, 2);
  MS_STEP_N(y0 - 2, 3); MS_STEP_N(y0 - 1, 4); MS_STEP_N(y0 + 0, 5);
  MS_STEP_N(y0 + 1, 6); MS_STEP_N(y0 + 2, 7); MS_STEP_N(y0 + 3, 8);
  MS_STEP_N(y0 + 4, 9);

  // Main: 11 phases per iteration; slot lists rotate by one each phase.
  for (int base = 0; base < nout; base += 11) {
    ROW_N(base + 0, 10, 0,1,2,3,4,5,6,7,8,9,10);
    ROW_N(base + 1, 0,  1,2,3,4,5,6,7,8,9,10,0);
    ROW_N(base + 2, 1,  2,3,4,5,6,7,8,9,10,0,1);
    ROW_N(base + 3, 2,  3,4,5,6,7,8,9,10,0,1,2);
    ROW_N(base + 4, 3,  4,5,6,7,8,9,10,0,1,2,3);
    ROW_N(base + 5, 4,  5,6,7,8,9,10,0,1,2,3,4);
    ROW_N(base + 6, 5,  6,7,8,9,10,0,1,2,3,4,5);
    ROW_N(base + 7, 6,  7,8,9,10,0,1,2,3,4,5,6);
    ROW_N(base + 8, 7,  8,9,10,0,1,2,3,4,5,6,7);
    ROW_N(base + 9, 8,  9,10,0,1,2,3,4,5,6,7,8);
    ROW_N(base + 10, 9, 10,0,1,2,3,4,5,6,7,8,9);
  }
  return sum;
}

template <int DS, int LAST>
__global__ __launch_bounds__(256)
void msssim_level_k(const float* __restrict__ P, const float* __restrict__ T,
                    const int H, const int W, const int strips,
                    const int chunks, const int chunkH, const int tasks,
                    float* __restrict__ dsP, float* __restrict__ dsT,
                    double* __restrict__ partial,
                    const float G0, const float G1, const float G2,
                    const float G3, const float G4, const float G5,
                    const float G6, const float G7, const float G8,
                    const float G9, const float G10) {
  __shared__ float sRed[4];
  const int tid = threadIdx.x;
  const int lane = tid & 63;
  const int wid = tid >> 6;
  float sum = 0.f;
  const int task = blockIdx.x * 4 + wid;
  if (task < tasks) {
    const int strip = task % strips;
    const int rem = task / strips;
    const int chunk = rem % chunks;
    const int img = rem / chunks;
    const int y0 = chunk * chunkH;
    const int nout = min(chunkH, H - y0);
    const size_t ibase = (size_t)img * H * W;
    const size_t obase = DS ? (size_t)img * (size_t)(H >> 1) * (W >> 1) : 0;
    const bool edge = (strip == 0) || (strip * 64 + 69 > W);  // wave-uniform
    if (edge)
      sum = strip_run<1, DS, LAST>(P + ibase, T + ibase, H, W, y0, nout,
                                   strip * 64, dsP, dsT, obase,
                                   G0, G1, G2, G3, G4, G5, G6, G7, G8, G9, G10);
    else
      sum = strip_run<0, DS, LAST>(P + ibase, T + ibase, H, W, y0, nout,
                                   strip * 64, dsP, dsT, obase,
                                   G0, G1, G2, G3, G4, G5, G6, G7, G8, G9, G10);
  }
#pragma unroll
  for (int off = 32; off; off >>= 1) sum += __shfl_down(sum, off, 64);
  if (lane == 0) sRed[wid] = sum;
  __syncthreads();
  if (tid == 0)
    partial[blockIdx.x] = (double)(sRed[0] + sRed[1] + sRed[2] + sRed[3]);
}

__global__ void msssim_combine_k(const double* __restrict__ partial,
                                 float* __restrict__ out, const CInfo ci) {
  const int lane = threadIdx.x & 63;
  double lv[5];
#pragma unroll
  for (int L = 0; L < 5; ++L) {
    double s = 0.0;
    for (int i = lane; i < ci.cnt[L]; i += 64) s += partial[ci.base[L] + i];
#pragma unroll
    for (int off = 32; off; off >>= 1) s += __shfl_down(s, off, 64);
    lv[L] = s;
  }
  if (lane == 0) {
    double ms = lv[4] / (48.0 * 32.0 * 32.0);
    ms *= pow(lv[0] / (48.0 * 512.0 * 512.0), (double)0.0448f);
    ms *= pow(lv[1] / (48.0 * 256.0 * 256.0), (double)0.2856f);
    ms *= pow(lv[2] / (48.0 * 128.0 * 128.0), (double)0.3001f);
    ms *= pow(lv[3] / (48.0 * 64.0 * 64.0),  (double)0.2363f);
    out[0] = (float)(1.0 - ms);
  }
}

extern "C" void kernel_launch(void* const* d_in, const int* in_sizes, int n_in,
                              void* d_out, int out_size, void* d_ws, size_t ws_size,
                              hipStream_t stream) {
  const float* pred = (const float*)d_in[0];
  const float* targ = (const float*)d_in[1];
  float* out = (float*)d_out;

  char* ws = (char*)d_ws;
  double* partial = (double*)ws;  // per-block partial sums, 32KB region
  size_t off = 32768;
  auto alloc = [&](size_t elems) {
    float* p = (float*)(ws + off);
    off += elems * sizeof(float);
    return p;
  };
  float* L1p = alloc((size_t)NIMG * 256 * 256);
  float* L1t = alloc((size_t)NIMG * 256 * 256);
  float* L2p = alloc((size_t)NIMG * 128 * 128);
  float* L2t = alloc((size_t)NIMG * 128 * 128);
  float* L3p = alloc((size_t)NIMG * 64 * 64);
  float* L3t = alloc((size_t)NIMG * 64 * 64);
  float* L4p = alloc((size_t)NIMG * 32 * 32);
  float* L4t = alloc((size_t)NIMG * 32 * 32);

  float g[11];
  {
    double gd[11], s = 0.0;
    for (int k = 0; k < 11; ++k) {
      const double c = (double)(k - 5);
      gd[k] = exp(-(c * c) / 4.5);  // 2*sigma^2 = 4.5
      s += gd[k];
    }
    for (int k = 0; k < 11; ++k) g[k] = (float)(gd[k] / s);
  }

  CInfo ci;
  int slotOff = 0;

  auto launchLevel = [&](const float* P, const float* T, int H, int W,
                         int chunkH, float* dP, float* dT, int L, bool last) {
    const int strips = (W + 63) / 64;
    const int chunks = (H + chunkH - 1) / chunkH;
    const int tasks = strips * chunks * NIMG;
    const int blocks = (tasks + 3) / 4;
    ci.base[L] = slotOff;
    ci.cnt[L] = blocks;
    if (last) {
      msssim_level_k<0, 1><<<blocks, 256, 0, stream>>>(
          P, T, H, W, strips, chunks, chunkH, tasks, nullptr, nullptr,
          partial + slotOff, g[0], g[1], g[2], g[3], g[4], g[5], g[6], g[7],
          g[8], g[9], g[10]);
    } else {
      msssim_level_k<1, 0><<<blocks, 256, 0, stream>>>(
          P, T, H, W, strips, chunks, chunkH, tasks, dP, dT,
          partial + slotOff, g[0], g[1], g[2], g[3], g[4], g[5], g[6], g[7],
          g[8], g[9], g[10]);
    }
    slotOff += blocks;
  };

  launchLevel(pred, targ, 512, 512, 32, L1p, L1t, 0, false);
  launchLevel(L1p, L1t, 256, 256, 16, L2p, L2t, 1, false);
  launchLevel(L2p, L2t, 128, 128, 8, L3p, L3t, 2, false);
  launchLevel(L3p, L3t, 64, 64, 8, L4p, L4t, 3, false);
  launchLevel(L4p, L4t, 32, 32, 8, nullptr, nullptr, 4, true);

  msssim_combine_k<<<1, 64, 0, stream>>>(partial, out, ci);
}